// Round 16
// baseline (326.836 us; speedup 1.0000x reference)
//
#include <hip/hip_runtime.h>

#define NS     32768
#define NA     2048
#define ASZ    1024
#define NB     4
#define SIGC   34848          /* padded shifted-copy length, mult of 16 */
#define BM     128
#define BN     128
#define BK     128
#define TILES  4096           /* (NA/BM)*(NS/BN) */
#define CAP    8192
#define MINT   5080           /* margin 2.0 in int units (2.0*127*20) */
#define SSCALE 20.0f
#define BSTR   1152           /* resident B row stride = 9*128 (bank-aligned groups) */
#define BSZ    18432          /* 16 rows * 1152 = 18 x 1KB chunks exactly */

typedef signed char s8;
typedef __attribute__((ext_vector_type(4))) int i32x4;
typedef __attribute__((ext_vector_type(16))) int i32x16;

__device__ __forceinline__ int imax(int a, int b) { return a > b ? a : b; }

// ---------------- prep (fused): A fragment-order prepack (32x32) + 16 shifted signal copies ----
// apack layout: 1KB block per (g, kt, ks), g=0..63 (32-row groups), kt=0..7, ks=0..3.
// Byte lane*16+j = quant(atoms[g*32+(lane&31)][kt*128+ks*32+16*(lane>>5)+j])
// = the 32x32x32 i8 MFMA A-fragment (layout HW-verified in R2). One coalesced 1KB read/frag.
__global__ void prep_k(const float* __restrict__ atoms, const float* __restrict__ orig,
                       s8* __restrict__ apack, s8* __restrict__ sigsh,
                       float* __restrict__ sigf, int* __restrict__ wlc) {
  if (blockIdx.x == 0 && threadIdx.x == 0) *wlc = 0;
  if (blockIdx.x < 512) {
    int g = blockIdx.x >> 3, kt = blockIdx.x & 7;
    int t = threadIdx.x;
    int ks = t >> 6, l = t & 63;
    int row = g * 32 + (l & 31);
    int kcol = kt * 128 + ks * 32 + 16 * (l >> 5);
    const float* srow = atoms + (size_t)row * ASZ + kcol;
    s8* dst = apack + ((size_t)((g * 8 + kt) * 4 + ks) << 10) + l * 16;
    #pragma unroll
    for (int j = 0; j < 16; j++) {
      float q = fminf(127.f, fmaxf(-127.f, srow[j] * 127.f));
      dst[j] = (s8)__float2int_rn(q);
    }
  } else {
    int r = blockIdx.x - 512;                // r = (b*16+m)*ceil(SIGC/256) + chunk
    int nch = (SIGC + 255) / 256;
    int bm = r / nch, chunk = r % nch;
    int i = chunk * 256 + threadIdx.x;
    if (i >= SIGC) return;
    int b = bm >> 4, m = bm & 15;
    int j = i + m - 512;
    float f = (j >= 0 && j < NS) ? orig[(size_t)b * NS + j] : 0.0f;
    float q = fminf(127.f, fmaxf(-127.f, f * SSCALE));
    sigsh[(size_t)bm * SIGC + i] = (s8)__float2int_rn(q);
    if (m == 0) sigf[(size_t)b * SIGC + i] = f;
  }
}

// ---------------- resident-B staging: 16 shift rows x 72 16B-slots, XOR-swizzled ----------------
// Logical: row m, slot s holds sig_logical[t0 + m + 16*s .. +15].
// Physical slot p = (s & ~7) | ((s ^ m) & 7); staged as 18 linear 1KB chunks,
// inverse swizzle applied on the GLOBAL source (rule #21).
__device__ __forceinline__ void stage_bsig(const s8* __restrict__ Sb, int t0,
                                           s8* Bsig, int w, int lane) {
  #pragma unroll
  for (int i = 0; i < 5; i++) {
    int c = w + 4 * i;                   // waves interleave chunks 0..17
    if (c < 18) {
      int o = c * 1024 + lane * 16;      // physical byte
      int m = o / BSTR;                  // row 0..15
      int pp = (o - m * BSTR) >> 4;      // physical slot 0..71
      int s = (pp & ~7) | ((pp ^ m) & 7);  // logical slot (involution)
      const s8* src = Sb + (size_t)m * SIGC + t0 + (s << 4);
      __builtin_amdgcn_global_load_lds((const __attribute__((address_space(1))) void*)src,
          (__attribute__((address_space(3))) void*)(&Bsig[c * 1024]), 16, 0, 0);
    }
  }
}

// ---------------- compute one K-tile: wave (wr,wc) owns 64x64 as 2x2 frags of 32x32x32 ----------
// A: ONE coalesced 1KB global read per frag (fragment-order apack, L2-resident).
// B: ds_read_b128 from resident swizzled Bsig; col c = wc*64+nf*32+(lane&31) decomposes to
// shift-row m=lane&15 and slot offset wc*4+nf*2+((lane>>4)&1); k adds kt*8+ks*2+(lane>>5).
__device__ __forceinline__ void compute_tile(const s8* __restrict__ Apk, const s8* Bsig, int kt,
                                             int w, int lane, i32x16 acc[2][2]) {
  int wr = w >> 1, wc = w & 1;
  int kg = lane >> 5;
  int m = lane & 15, mx = m & 7;
  const s8* brow = Bsig + m * BSTR;
  int sbase = wc * 4 + ((lane >> 4) & 1) + kt * 8 + kg;
  const s8* abase = Apk + ((size_t)(((wr * 2) * 8 + kt) * 4) << 10) + (lane << 4);
  #pragma unroll
  for (int ks = 0; ks < 4; ks++) {
    i32x4 af[2], bfr[2];
    #pragma unroll
    for (int mf = 0; mf < 2; mf++)
      af[mf] = *(const i32x4*)&abase[((size_t)(mf * 32 + ks) << 10)];  // mf: +32KB, ks: +1KB
    #pragma unroll
    for (int nf = 0; nf < 2; nf++) {
      int s = sbase + nf * 2 + ks * 2;     // logical slot <= 70
      int ps = (s & ~7) | ((s ^ mx) & 7);  // XOR swizzle (matches staging)
      bfr[nf] = *(const i32x4*)&brow[ps << 4];
    }
    __builtin_amdgcn_s_setprio(1);
    #pragma unroll
    for (int mf = 0; mf < 2; mf++)
      #pragma unroll
      for (int nf = 0; nf < 2; nf++)
        acc[mf][nf] = __builtin_amdgcn_mfma_i32_32x32x32_i8(af[mf], bfr[nf], acc[mf][nf], 0, 0, 0);
    __builtin_amdgcn_s_setprio(0);
  }
}

// Barrier-free K loop: one staged barrier for Bsig, then free-running MFMA + coalesced A loads.
#define K_LOOP(Apk, Sb, t0)                                   \
  stage_bsig(Sb, t0, Bsig, w, lane);                          \
  __syncthreads();                                            \
  _Pragma("unroll 2")                                         \
  for (int kt = 0; kt < 8; kt++)                              \
    compute_tile(Apk, Sb##sig, kt, w, lane, acc);

// ---------------- pass 1: i8 screening GEMM, per-tile max (exact int32) ----------------
__global__ __launch_bounds__(256, 4)
void screen1(const s8* __restrict__ apack, const s8* __restrict__ sigsh,
             int* __restrict__ tmax)
{
  __shared__ __align__(16) s8 Bsig[BSZ];       // 18 KB resident signal copies
  __shared__ int wred[4];
  int bid0 = blockIdx.x;
  int bid  = (bid0 & 7) * ((NB * TILES) >> 3) + (bid0 >> 3);   // XCD swizzle (16384 % 8 == 0)
  int b = bid >> 12, tile = bid & 4095;
  int mt = tile >> 8, nt = tile & 255;
  int m0 = mt * BM, t0 = nt * BN;
  int tid = threadIdx.x, w = tid >> 6, lane = tid & 63;
  const s8* Apk = apack + (size_t)mt * 131072;   // mt * 4 groups * 32KB
  const s8* Sb = sigsh + (size_t)b * 16 * SIGC;

  i32x16 acc[2][2];
  #pragma unroll
  for (int i = 0; i < 2; i++)
    #pragma unroll
    for (int j = 0; j < 2; j++)
      #pragma unroll
      for (int q = 0; q < 16; q++) acc[i][j][q] = 0;

  stage_bsig(Sb, t0, Bsig, w, lane);
  __syncthreads();
  #pragma unroll 2
  for (int kt = 0; kt < 8; kt++)
    compute_tile(Apk, Bsig, kt, w, lane, acc);

  int lmax = -2147483647;
  #pragma unroll
  for (int mf = 0; mf < 2; mf++)
    #pragma unroll
    for (int nf = 0; nf < 2; nf++)
      #pragma unroll
      for (int q = 0; q < 16; q++) lmax = imax(lmax, acc[mf][nf][q]);
  #pragma unroll
  for (int off = 32; off; off >>= 1) lmax = imax(lmax, __shfl_xor(lmax, off, 64));
  if (lane == 0) wred[w] = lmax;
  __syncthreads();
  if (tid == 0)
    tmax[b * TILES + tile] = imax(imax(wred[0], wred[1]), imax(wred[2], wred[3]));
}

// ---------------- threshold: 64th-largest tile-max (2-level histogram) + worklist ----------------
__global__ void thresh_k(const int* __restrict__ tmax, int* __restrict__ thr,
                         int* __restrict__ ccnt, int* __restrict__ wl, int* __restrict__ wlc) {
  int b = blockIdx.x, tid = threadIdx.x;
  __shared__ int hist[4096];
  __shared__ int tsum[256];
  __shared__ int hist2[256];
  __shared__ int sB1, sAbove, sThr;
  for (int i = tid; i < 4096; i += 256) hist[i] = 0;
  __syncthreads();
  for (int i = tid; i < TILES; i += 256) {
    unsigned u = (unsigned)tmax[b * TILES + i] ^ 0x80000000u;
    atomicAdd(&hist[u >> 20], 1);
  }
  __syncthreads();
  { int s = 0;
    for (int j = 0; j < 16; j++) s += hist[tid * 16 + j];
    tsum[tid] = s; }
  __syncthreads();
  if (tid == 0) {
    int cum = 0, T = 0;
    for (int t2 = 255; t2 >= 0; t2--) {
      if (cum + tsum[t2] >= 64) { T = t2; break; }
      cum += tsum[t2];
    }
    int B1 = T * 16;
    for (int bk = T * 16 + 15; bk >= T * 16; bk--) {
      if (cum + hist[bk] >= 64) { B1 = bk; break; }
      cum += hist[bk];
    }
    sB1 = B1; sAbove = cum;
  }
  __syncthreads();
  if (tid < 256) hist2[tid] = 0;
  __syncthreads();
  int B1 = sB1;
  for (int i = tid; i < TILES; i += 256) {
    unsigned u = (unsigned)tmax[b * TILES + i] ^ 0x80000000u;
    if ((int)(u >> 20) == B1) atomicAdd(&hist2[(u >> 12) & 255], 1);
  }
  __syncthreads();
  if (tid == 0) {
    int cum = sAbove, B2 = 0;
    for (int z = 255; z >= 0; z--) { cum += hist2[z]; if (cum >= 64) { B2 = z; break; } }
    unsigned ulow = ((unsigned)B1 << 20) | ((unsigned)B2 << 12);
    int t = (int)(ulow ^ 0x80000000u);
    sThr = t; thr[b] = t; ccnt[b] = 0;
  }
  __syncthreads();
  int cut = sThr - MINT;
  for (int i = tid; i < TILES; i += 256)
    if (tmax[b * TILES + i] >= cut) { int p = atomicAdd(wlc, 1); wl[p] = (b << 12) | i; }
}

// ---------------- pass 2: recompute gated tiles from worklist, emit candidate indices ----------------
__global__ __launch_bounds__(256, 4)
void screen2(const s8* __restrict__ apack, const s8* __restrict__ sigsh,
             const int* __restrict__ thr, const int* __restrict__ wl,
             const int* __restrict__ wlc, int* __restrict__ ccnt, int* __restrict__ cidx)
{
  __shared__ __align__(16) s8 Bsig[BSZ];
  int n = *wlc; if (n > NB * TILES) n = NB * TILES;
  int tid = threadIdx.x, w = tid >> 6, lane = tid & 63;
  int wr = w >> 1, wc = w & 1;

  for (int wi = blockIdx.x; wi < n; wi += gridDim.x) {
    int e = wl[wi];
    int b = e >> 12, tile = e & 4095;
    int cut = thr[b] - MINT;
    int mt = tile >> 8, nt = tile & 255;
    int m0 = mt * BM, t0 = nt * BN;
    const s8* Apk = apack + (size_t)mt * 131072;
    const s8* Sb = sigsh + (size_t)b * 16 * SIGC;

    i32x16 acc[2][2];
    #pragma unroll
    for (int i = 0; i < 2; i++)
      #pragma unroll
      for (int j = 0; j < 2; j++)
        #pragma unroll
        for (int q = 0; q < 16; q++) acc[i][j][q] = 0;

    stage_bsig(Sb, t0, Bsig, w, lane);
    __syncthreads();
    #pragma unroll 2
    for (int kt = 0; kt < 8; kt++)
      compute_tile(Apk, Bsig, kt, w, lane, acc);

    // C/D 32x32 (R2-verified): row = (q&3)+8*(q>>2)+4*(lane>>5), col = lane&31
    int rb = m0 + wr * 64 + 4 * (lane >> 5);
    int cb = t0 + wc * 64 + (lane & 31);
    #pragma unroll
    for (int mf = 0; mf < 2; mf++)
      #pragma unroll
      for (int nf = 0; nf < 2; nf++)
        #pragma unroll
        for (int q = 0; q < 16; q++) {
          if (acc[mf][nf][q] >= cut) {
            int a = rb + mf * 32 + (q & 3) + 8 * (q >> 2);
            int t = cb + nf * 32;
            int p = atomicAdd(&ccnt[b], 1);
            if (p < CAP) cidx[b * CAP + p] = (a << 15) | t;
          }
        }
    __syncthreads();                         // all waves done with Bsig before restage
  }
}

// ---------------- rescore candidates exactly in fp32 (grid-stride waves) ----------------
__global__ void rescore_k(const float* __restrict__ atoms, const float* __restrict__ sigf,
                          const int* __restrict__ ccnt, const int* __restrict__ cidx,
                          float* __restrict__ cval) {
  int nwv = gridDim.x * 4;
  int gw = blockIdx.x * 4 + (threadIdx.x >> 6);
  int lane = threadIdx.x & 63;
  for (int b = 0; b < NB; b++) {
    int cnt = ccnt[b]; if (cnt > CAP) cnt = CAP;
    for (int ci = gw; ci < cnt; ci += nwv) {
      int idx = cidx[b * CAP + ci];
      int a = idx >> 15, t = idx & (NS - 1);
      const float* ap = atoms + (size_t)a * ASZ;
      const float* sp = sigf + (size_t)b * SIGC + t;
      float sum = 0.f;
      #pragma unroll
      for (int j = 0; j < 16; j++) { int k = lane + 64 * j; sum += ap[k] * sp[k]; }
      #pragma unroll
      for (int off = 32; off; off >>= 1) sum += __shfl_xor(sum, off, 64);
      if (lane == 0) cval[b * CAP + ci] = sum;
    }
  }
}

// ---------------- select top-64 per batch by rank counting (value desc, tie: index asc) ----------------
__global__ void select_k(const int* __restrict__ ccnt, const float* __restrict__ cval,
                         const int* __restrict__ cidx, float* __restrict__ sval,
                         int* __restrict__ sidx) {
  int b = blockIdx.x, tid = threadIdx.x;
  int cnt = ccnt[b]; if (cnt > CAP) cnt = CAP;
  __shared__ float lv[2048];
  __shared__ int li[2048];
  for (int ii = 0; ii * 256 < cnt; ii++) {
    int i = ii * 256 + tid;
    float vi = 0.f; int idi = 0; bool act = i < cnt;
    if (act) { vi = cval[b * CAP + i]; idi = cidx[b * CAP + i]; }
    int rank = 0;
    for (int c0 = 0; c0 < cnt; c0 += 2048) {
      int mchunk = cnt - c0; if (mchunk > 2048) mchunk = 2048;
      __syncthreads();
      for (int j = tid; j < mchunk; j += 256) {
        lv[j] = cval[b * CAP + c0 + j];
        li[j] = cidx[b * CAP + c0 + j];
      }
      __syncthreads();
      if (act)
        for (int j = 0; j < mchunk; j++)
          rank += (lv[j] > vi) || (lv[j] == vi && li[j] < idi);
    }
    if (act && rank < 64) { sval[b * 64 + rank] = vi; sidx[b * 64 + rank] = idi; }
  }
}

// ---------------- deterministic reconstruction (one thread per output sample) ----------------
__global__ void recon_k(const float* __restrict__ atoms, const float* __restrict__ sval,
                        const int* __restrict__ sidx, float* __restrict__ out) {
  int gp = blockIdx.x * 256 + threadIdx.x;       // 0 .. NB*NS-1
  int b = gp >> 15, p = gp & (NS - 1);
  __shared__ float vv[64];
  __shared__ int ii[64];
  if (threadIdx.x < 64) {
    vv[threadIdx.x] = sval[b * 64 + threadIdx.x];
    ii[threadIdx.x] = sidx[b * 64 + threadIdx.x];
  }
  __syncthreads();
  float acc = 0.f;
  for (int s = 0; s < 64; s++) {
    int idx = ii[s];
    int a = idx >> 15, t = idx & (NS - 1);
    int off = p - t;
    if (off >= 0 && off < ASZ) acc += vv[s] * atoms[(size_t)a * ASZ + off];
  }
  out[gp] = acc;
}

extern "C" void kernel_launch(void* const* d_in, const int* in_sizes, int n_in,
                              void* d_out, int out_size, void* d_ws, size_t ws_size,
                              hipStream_t stream) {
  const float* orig  = (const float*)d_in[0];   // (4,1,32768) fp32
  const float* atoms = (const float*)d_in[1];   // (2048,1024) fp32
  float* out = (float*)d_out;                   // (4,1,32768) fp32
  char* ws = (char*)d_ws;

  // workspace layout (16B-aligned), total ~5.3 MB
  s8*    apack = (s8*)   (ws + 0);          // 2,097,152 : atoms i8, 32x32 MFMA fragment order
  s8*    sigsh = (s8*)   (ws + 2097152);    // 2,230,272 : 16 shifted padded i8 signal copies
  float* sigf  = (float*)(ws + 4327424);    //   557,568 : padded signal fp32
  int*   tmax  = (int*)  (ws + 4884992);    //    65,536 : per-tile maxima (int)
  int*   thr   = (int*)  (ws + 4950528);    //       256 : per-batch threshold (int)
  int*   ccnt  = (int*)  (ws + 4950784);    //       256 : candidate counts
  float* cval  = (float*)(ws + 4951040);    //   131,072 : candidate exact fp32 values
  int*   cidx  = (int*)  (ws + 5082112);    //   131,072 : candidate flat indices
  float* sval  = (float*)(ws + 5213184);    //     1,024 : selected values
  int*   sidx  = (int*)  (ws + 5214208);    //     1,024 : selected indices
  int*   wl    = (int*)  (ws + 5215232);    //    65,536 : gated-tile worklist
  int*   wlc   = (int*)  (ws + 5280768);    //       256 : worklist count

  int nch = (SIGC + 255) / 256;
  prep_k<<<512 + NB * 16 * nch, 256, 0, stream>>>(atoms, orig, apack, sigsh, sigf, wlc);
  screen1<<<NB * TILES, 256, 0, stream>>>(apack, sigsh, tmax);
  thresh_k<<<NB, 256, 0, stream>>>(tmax, thr, ccnt, wl, wlc);
  screen2<<<512, 256, 0, stream>>>(apack, sigsh, thr, wl, wlc, ccnt, cidx);
  rescore_k<<<128, 256, 0, stream>>>(atoms, sigf, ccnt, cidx, cval);
  select_k<<<NB, 256, 0, stream>>>(ccnt, cval, cidx, sval, sidx);
  recon_k<<<out_size / 256, 256, 0, stream>>>(atoms, sval, sidx, out);
}

// Round 17
// 268.752 us; speedup vs baseline: 1.2161x; 1.2161x over previous
//
#include <hip/hip_runtime.h>

#define NS     32768
#define NA     2048
#define ASZ    1024
#define NB     4
#define SIGC   34848          /* padded shifted-copy length, mult of 16 */
#define BM     128
#define BN     256
#define TILES  2048           /* (NA/BM)*(NS/BN) = 16*128 */
#define CAP    8192
#define MINT   5080           /* margin 2.0 in int units (2.0*127*20) */
#define SSCALE 20.0f
#define BSTR   1280           /* resident B row stride = 10*128 (bank-aligned groups) */
#define BSZ    20480          /* 16 rows * 1280 = 20 x 1KB chunks exactly */

typedef signed char s8;
typedef __attribute__((ext_vector_type(4))) int i32x4;

__device__ __forceinline__ int imax(int a, int b) { return a > b ? a : b; }

// ---------------- prep (fused): A fragment-order prepack + 16 shifted signal copies ----------------
// apack layout: 1KB block per (g, kt, kk), g=0..127 (16-row groups), kt=0..7, kk=0..1.
// Byte lane*16+j of block = quant(atoms[g*16+(lane&15)][kt*128+(kk*4+(lane>>4))*16+j]).
// A wave's (mf,kk) MFMA A-fragment is then ONE fully-coalesced 1KB read: base + lane*16.
__global__ void prep_k(const float* __restrict__ atoms, const float* __restrict__ orig,
                       s8* __restrict__ apack, s8* __restrict__ sigsh,
                       float* __restrict__ sigf, int* __restrict__ wlc) {
  if (blockIdx.x == 0 && threadIdx.x == 0) *wlc = 0;
  if (blockIdx.x < 1024) {
    int g = blockIdx.x >> 3, kt = blockIdx.x & 7;
    int t = threadIdx.x;
    int kk = t >> 7, r = t & 127, l = r >> 1, half = r & 1;
    int row = g * 16 + (l & 15);
    int kbase = kt * 128 + (kk * 4 + (l >> 4)) * 16 + half * 8;
    const float* srow = atoms + (size_t)row * ASZ + kbase;
    s8* dst = apack + (size_t)(((g * 8 + kt) * 2 + kk) << 10) + l * 16 + half * 8;
    #pragma unroll
    for (int j = 0; j < 8; j++) {
      float q = fminf(127.f, fmaxf(-127.f, srow[j] * 127.f));
      dst[j] = (s8)__float2int_rn(q);
    }
  } else {
    int r = blockIdx.x - 1024;               // r = (b*16+m)*ceil(SIGC/256) + chunk
    int nch = (SIGC + 255) / 256;
    int bm = r / nch, chunk = r % nch;
    int i = chunk * 256 + threadIdx.x;
    if (i >= SIGC) return;
    int b = bm >> 4, m = bm & 15;
    int j = i + m - 512;
    float f = (j >= 0 && j < NS) ? orig[(size_t)b * NS + j] : 0.0f;
    float q = fminf(127.f, fmaxf(-127.f, f * SSCALE));
    sigsh[(size_t)bm * SIGC + i] = (s8)__float2int_rn(q);
    if (m == 0) sigf[(size_t)b * SIGC + i] = f;
  }
}

// ---------------- resident-B staging: 16 shift rows x 80 16B-slots, XOR-swizzled ----------------
// Logical: row m, slot s holds sig_logical[t0 + m + 16*s .. +15].
// Physical slot p = (s & ~7) | ((s ^ m) & 7); staged as 20 linear 1KB chunks,
// inverse swizzle applied on the GLOBAL source (rule #21). 8 waves interleave chunks.
__device__ __forceinline__ void stage_bsig(const s8* __restrict__ Sb, int t0,
                                           s8* Bsig, int w, int lane) {
  #pragma unroll
  for (int i = 0; i < 3; i++) {
    int c = w + 8 * i;                   // chunks 0..19
    if (c < 20) {
      int o = c * 1024 + lane * 16;      // physical byte
      int m = o / BSTR;                  // row 0..15
      int pp = (o - m * BSTR) >> 4;      // physical slot 0..79
      int s = (pp & ~7) | ((pp ^ m) & 7);  // logical slot (involution)
      const s8* src = Sb + (size_t)m * SIGC + t0 + (s << 4);
      __builtin_amdgcn_global_load_lds((const __attribute__((address_space(1))) void*)src,
          (__attribute__((address_space(3))) void*)(&Bsig[c * 1024]), 16, 0, 0);
    }
  }
}

// ---------------- compute one K-tile: wave (wr=w>>2, wc=w&3) owns 64x64, 4x4 frags of 16x16x64 ----
// A fragments: ONE coalesced 1KB global read each (fragment-order apack, L2-resident;
// 4 waves share each fragment -> L1 dedupes). B: ds_read_b128 from resident swizzled Bsig.
__device__ __forceinline__ void compute_tile(const s8* __restrict__ Apk, const s8* Bsig, int kt,
                                             int w, int lane, i32x4 acc[4][4]) {
  int wr = w >> 2, wc = w & 3;
  int kgrp = lane >> 4;
  int m = lane & 15, mx = m & 7;
  const s8* brow = Bsig + m * BSTR;
  const s8* abase = Apk + ((((size_t)wr * 4 * 8 + kt) * 2) << 10) + (lane << 4);
  int sb = wc * 4 + kgrp + kt * 8;         // runtime base of logical B slot
  #pragma unroll
  for (int kk = 0; kk < 2; kk++) {
    i32x4 af[4], bfr[4];
    #pragma unroll
    for (int mf = 0; mf < 4; mf++)
      af[mf] = *(const i32x4*)&abase[((mf * 16 + kk) << 10)];   // mf: +16KB, kk: +1KB
    #pragma unroll
    for (int nf = 0; nf < 4; nf++) {
      int s = sb + nf + kk * 4;            // logical slot <= 74
      int ps = (s & ~7) | ((s ^ mx) & 7);  // XOR swizzle (matches staging)
      bfr[nf] = *(const i32x4*)&brow[ps << 4];
    }
    __builtin_amdgcn_s_setprio(1);
    #pragma unroll
    for (int mf = 0; mf < 4; mf++)
      #pragma unroll
      for (int nf = 0; nf < 4; nf++)
        acc[mf][nf] = __builtin_amdgcn_mfma_i32_16x16x64_i8(af[mf], bfr[nf], acc[mf][nf], 0, 0, 0);
    __builtin_amdgcn_s_setprio(0);
  }
}

// ---------------- pass 1: i8 screening GEMM, per-tile max (exact int32) ----------------
__global__ __launch_bounds__(512, 4)
void screen1(const s8* __restrict__ apack, const s8* __restrict__ sigsh,
             int* __restrict__ tmax)
{
  __shared__ __align__(16) s8 Bsig[BSZ];       // 20 KB resident signal copies
  __shared__ int wred[8];
  int bid0 = blockIdx.x;
  int bid  = (bid0 & 7) * ((NB * TILES) >> 3) + (bid0 >> 3);   // XCD swizzle (8192 % 8 == 0)
  int b = bid >> 11, tile = bid & (TILES - 1);
  int mt = tile >> 7, nt = tile & 127;
  int m0 = mt * BM, t0 = nt * BN;
  int tid = threadIdx.x, w = tid >> 6, lane = tid & 63;
  const s8* Apk = apack + (size_t)mt * 131072;   // mt * 8 groups * 16KB
  const s8* Sb = sigsh + (size_t)b * 16 * SIGC;

  i32x4 acc[4][4];
  #pragma unroll
  for (int i = 0; i < 4; i++)
    #pragma unroll
    for (int j = 0; j < 4; j++) acc[i][j] = (i32x4){0, 0, 0, 0};

  stage_bsig(Sb, t0, Bsig, w, lane);
  __syncthreads();
  #pragma unroll 2
  for (int kt = 0; kt < 8; kt++)
    compute_tile(Apk, Bsig, kt, w, lane, acc);

  int lmax = -2147483647;
  #pragma unroll
  for (int mf = 0; mf < 4; mf++)
    #pragma unroll
    for (int nf = 0; nf < 4; nf++)
      #pragma unroll
      for (int q = 0; q < 4; q++) lmax = imax(lmax, acc[mf][nf][q]);
  #pragma unroll
  for (int off = 32; off; off >>= 1) lmax = imax(lmax, __shfl_xor(lmax, off, 64));
  if (lane == 0) wred[w] = lmax;
  __syncthreads();
  if (tid == 0) {
    int mm = wred[0];
    #pragma unroll
    for (int i = 1; i < 8; i++) mm = imax(mm, wred[i]);
    tmax[b * TILES + tile] = mm;
  }
}

// ---------------- threshold: 64th-largest tile-max (2-level histogram) + worklist ----------------
__global__ void thresh_k(const int* __restrict__ tmax, int* __restrict__ thr,
                         int* __restrict__ ccnt, int* __restrict__ wl, int* __restrict__ wlc) {
  int b = blockIdx.x, tid = threadIdx.x;
  __shared__ int hist[4096];
  __shared__ int tsum[256];
  __shared__ int hist2[256];
  __shared__ int sB1, sAbove, sThr;
  for (int i = tid; i < 4096; i += 256) hist[i] = 0;
  __syncthreads();
  for (int i = tid; i < TILES; i += 256) {
    unsigned u = (unsigned)tmax[b * TILES + i] ^ 0x80000000u;
    atomicAdd(&hist[u >> 20], 1);
  }
  __syncthreads();
  { int s = 0;
    for (int j = 0; j < 16; j++) s += hist[tid * 16 + j];
    tsum[tid] = s; }
  __syncthreads();
  if (tid == 0) {
    int cum = 0, T = 0;
    for (int t2 = 255; t2 >= 0; t2--) {
      if (cum + tsum[t2] >= 64) { T = t2; break; }
      cum += tsum[t2];
    }
    int B1 = T * 16;
    for (int bk = T * 16 + 15; bk >= T * 16; bk--) {
      if (cum + hist[bk] >= 64) { B1 = bk; break; }
      cum += hist[bk];
    }
    sB1 = B1; sAbove = cum;
  }
  __syncthreads();
  if (tid < 256) hist2[tid] = 0;
  __syncthreads();
  int B1 = sB1;
  for (int i = tid; i < TILES; i += 256) {
    unsigned u = (unsigned)tmax[b * TILES + i] ^ 0x80000000u;
    if ((int)(u >> 20) == B1) atomicAdd(&hist2[(u >> 12) & 255], 1);
  }
  __syncthreads();
  if (tid == 0) {
    int cum = sAbove, B2 = 0;
    for (int z = 255; z >= 0; z--) { cum += hist2[z]; if (cum >= 64) { B2 = z; break; } }
    unsigned ulow = ((unsigned)B1 << 20) | ((unsigned)B2 << 12);
    int t = (int)(ulow ^ 0x80000000u);
    sThr = t; thr[b] = t; ccnt[b] = 0;
  }
  __syncthreads();
  int cut = sThr - MINT;
  for (int i = tid; i < TILES; i += 256)
    if (tmax[b * TILES + i] >= cut) { int p = atomicAdd(wlc, 1); wl[p] = (b << 11) | i; }
}

// ---------------- pass 2: recompute gated tiles from worklist, emit candidate indices ----------------
__global__ __launch_bounds__(512, 4)
void screen2(const s8* __restrict__ apack, const s8* __restrict__ sigsh,
             const int* __restrict__ thr, const int* __restrict__ wl,
             const int* __restrict__ wlc, int* __restrict__ ccnt, int* __restrict__ cidx)
{
  __shared__ __align__(16) s8 Bsig[BSZ];
  int n = *wlc; if (n > NB * TILES) n = NB * TILES;
  int tid = threadIdx.x, w = tid >> 6, lane = tid & 63;
  int wr = w >> 2, wc = w & 3;
  int kgrp = lane >> 4;

  for (int wi = blockIdx.x; wi < n; wi += gridDim.x) {
    int e = wl[wi];
    int b = e >> 11, tile = e & (TILES - 1);
    int cut = thr[b] - MINT;
    int mt = tile >> 7, nt = tile & 127;
    int m0 = mt * BM, t0 = nt * BN;
    const s8* Apk = apack + (size_t)mt * 131072;
    const s8* Sb = sigsh + (size_t)b * 16 * SIGC;

    i32x4 acc[4][4];
    #pragma unroll
    for (int i = 0; i < 4; i++)
      #pragma unroll
      for (int j = 0; j < 4; j++) acc[i][j] = (i32x4){0, 0, 0, 0};

    stage_bsig(Sb, t0, Bsig, w, lane);
    __syncthreads();
    #pragma unroll 2
    for (int kt = 0; kt < 8; kt++)
      compute_tile(Apk, Bsig, kt, w, lane, acc);

    int rb = m0 + wr * 64 + 4 * kgrp;
    int cb = t0 + wc * 64 + (lane & 15);
    #pragma unroll
    for (int mf = 0; mf < 4; mf++)
      #pragma unroll
      for (int nf = 0; nf < 4; nf++)
        #pragma unroll
        for (int q = 0; q < 4; q++) {
          if (acc[mf][nf][q] >= cut) {
            int a = rb + mf * 16 + q;        // C/D 16x16: row=(lane>>4)*4+reg
            int t = cb + nf * 16;            //           col=lane&15
            int p = atomicAdd(&ccnt[b], 1);
            if (p < CAP) cidx[b * CAP + p] = (a << 15) | t;
          }
        }
    __syncthreads();                         // all waves done with Bsig before restage
  }
}

// ---------------- rescore candidates exactly in fp32 (grid-stride waves) ----------------
__global__ void rescore_k(const float* __restrict__ atoms, const float* __restrict__ sigf,
                          const int* __restrict__ ccnt, const int* __restrict__ cidx,
                          float* __restrict__ cval) {
  int nwv = gridDim.x * 4;
  int gw = blockIdx.x * 4 + (threadIdx.x >> 6);
  int lane = threadIdx.x & 63;
  for (int b = 0; b < NB; b++) {
    int cnt = ccnt[b]; if (cnt > CAP) cnt = CAP;
    for (int ci = gw; ci < cnt; ci += nwv) {
      int idx = cidx[b * CAP + ci];
      int a = idx >> 15, t = idx & (NS - 1);
      const float* ap = atoms + (size_t)a * ASZ;
      const float* sp = sigf + (size_t)b * SIGC + t;
      float sum = 0.f;
      #pragma unroll
      for (int j = 0; j < 16; j++) { int k = lane + 64 * j; sum += ap[k] * sp[k]; }
      #pragma unroll
      for (int off = 32; off; off >>= 1) sum += __shfl_xor(sum, off, 64);
      if (lane == 0) cval[b * CAP + ci] = sum;
    }
  }
}

// ---------------- select top-64 per batch by rank counting (value desc, tie: index asc) ----------------
__global__ void select_k(const int* __restrict__ ccnt, const float* __restrict__ cval,
                         const int* __restrict__ cidx, float* __restrict__ sval,
                         int* __restrict__ sidx) {
  int b = blockIdx.x, tid = threadIdx.x;
  int cnt = ccnt[b]; if (cnt > CAP) cnt = CAP;
  __shared__ float lv[2048];
  __shared__ int li[2048];
  for (int ii = 0; ii * 256 < cnt; ii++) {
    int i = ii * 256 + tid;
    float vi = 0.f; int idi = 0; bool act = i < cnt;
    if (act) { vi = cval[b * CAP + i]; idi = cidx[b * CAP + i]; }
    int rank = 0;
    for (int c0 = 0; c0 < cnt; c0 += 2048) {
      int mchunk = cnt - c0; if (mchunk > 2048) mchunk = 2048;
      __syncthreads();
      for (int j = tid; j < mchunk; j += 256) {
        lv[j] = cval[b * CAP + c0 + j];
        li[j] = cidx[b * CAP + c0 + j];
      }
      __syncthreads();
      if (act)
        for (int j = 0; j < mchunk; j++)
          rank += (lv[j] > vi) || (lv[j] == vi && li[j] < idi);
    }
    if (act && rank < 64) { sval[b * 64 + rank] = vi; sidx[b * 64 + rank] = idi; }
  }
}

// ---------------- deterministic reconstruction (one thread per output sample) ----------------
__global__ void recon_k(const float* __restrict__ atoms, const float* __restrict__ sval,
                        const int* __restrict__ sidx, float* __restrict__ out) {
  int gp = blockIdx.x * 256 + threadIdx.x;       // 0 .. NB*NS-1
  int b = gp >> 15, p = gp & (NS - 1);
  __shared__ float vv[64];
  __shared__ int ii[64];
  if (threadIdx.x < 64) {
    vv[threadIdx.x] = sval[b * 64 + threadIdx.x];
    ii[threadIdx.x] = sidx[b * 64 + threadIdx.x];
  }
  __syncthreads();
  float acc = 0.f;
  for (int s = 0; s < 64; s++) {
    int idx = ii[s];
    int a = idx >> 15, t = idx & (NS - 1);
    int off = p - t;
    if (off >= 0 && off < ASZ) acc += vv[s] * atoms[(size_t)a * ASZ + off];
  }
  out[gp] = acc;
}

extern "C" void kernel_launch(void* const* d_in, const int* in_sizes, int n_in,
                              void* d_out, int out_size, void* d_ws, size_t ws_size,
                              hipStream_t stream) {
  const float* orig  = (const float*)d_in[0];   // (4,1,32768) fp32
  const float* atoms = (const float*)d_in[1];   // (2048,1024) fp32
  float* out = (float*)d_out;                   // (4,1,32768) fp32
  char* ws = (char*)d_ws;

  // workspace layout (16B-aligned), total ~5.3 MB
  s8*    apack = (s8*)   (ws + 0);          // 2,097,152 : atoms i8, MFMA fragment order
  s8*    sigsh = (s8*)   (ws + 2097152);    // 2,230,272 : 16 shifted padded i8 signal copies
  float* sigf  = (float*)(ws + 4327424);    //   557,568 : padded signal fp32
  int*   tmax  = (int*)  (ws + 4884992);    //    32,768 : per-tile maxima (int)
  int*   thr   = (int*)  (ws + 4917760);    //       256 : per-batch threshold (int)
  int*   ccnt  = (int*)  (ws + 4918016);    //       256 : candidate counts
  float* cval  = (float*)(ws + 4918272);    //   131,072 : candidate exact fp32 values
  int*   cidx  = (int*)  (ws + 5049344);    //   131,072 : candidate flat indices
  float* sval  = (float*)(ws + 5180416);    //     1,024 : selected values
  int*   sidx  = (int*)  (ws + 5181440);    //     1,024 : selected indices
  int*   wl    = (int*)  (ws + 5182464);    //    32,768 : gated-tile worklist
  int*   wlc   = (int*)  (ws + 5215232);    //       256 : worklist count

  int nch = (SIGC + 255) / 256;
  prep_k<<<1024 + NB * 16 * nch, 256, 0, stream>>>(atoms, orig, apack, sigsh, sigf, wlc);
  screen1<<<NB * TILES, 512, 0, stream>>>(apack, sigsh, tmax);
  thresh_k<<<NB, 256, 0, stream>>>(tmax, thr, ccnt, wl, wlc);
  screen2<<<256, 512, 0, stream>>>(apack, sigsh, thr, wl, wlc, ccnt, cidx);
  rescore_k<<<128, 256, 0, stream>>>(atoms, sigf, ccnt, cidx, cval);
  select_k<<<NB, 256, 0, stream>>>(ccnt, cval, cidx, sval, sidx);
  recon_k<<<out_size / 256, 256, 0, stream>>>(atoms, sval, sidx, out);
}